// Round 1
// baseline (257.833 us; speedup 1.0000x reference)
//
#include <hip/hip_runtime.h>
#include <cstdint>
#include <cstddef>

#define DEV static __device__ __forceinline__

typedef __attribute__((ext_vector_type(8))) short bf16x8;   // 8 bf16 (4 VGPRs)
typedef __attribute__((ext_vector_type(4))) float f32x4;

constexpr int NB   = 64;     // batch
constexpr int NTOK = 197;    // tokens
constexpr int DIMC = 768;    // channels
constexpr int NH   = 12;     // heads
constexpr int HDIM = 64;     // head dim
constexpr int MTOK = NB * NTOK;   // 12608 rows
constexpr int QKVO = 3 * DIMC;    // 2304

DEV unsigned short f2bf(float f) {
  union { float f; uint32_t u; } v; v.f = f;
  uint32_t u = v.u;
  return (unsigned short)((u + 0x7FFFu + ((u >> 16) & 1u)) >> 16);  // RNE, finite inputs
}

DEV f32x4 mfma16(bf16x8 a, bf16x8 b, f32x4 c) {
  return __builtin_amdgcn_mfma_f32_16x16x32_bf16(a, b, c, 0, 0, 0);
}

DEV void async_cp16(const unsigned short* g, unsigned short* l) {
  // direct global->LDS DMA, 16B/lane; LDS dest is lane-contiguous (no pad!)
  __builtin_amdgcn_global_load_lds(
      (__attribute__((address_space(1))) void*)g,
      (__attribute__((address_space(3))) void*)l, 16, 0, 0);
}

// ---------------- f32 -> bf16 convert (memory-bound) ----------------
__global__ void __launch_bounds__(256) cvt_bf16(const float* __restrict__ s,
                                                unsigned short* __restrict__ d, int n) {
  int i = (blockIdx.x * 256 + threadIdx.x) * 4;
  if (i < n) {
    float4 f = *(const float4*)(s + i);
    ushort4 o;
    o.x = f2bf(f.x); o.y = f2bf(f.y); o.z = f2bf(f.z); o.w = f2bf(f.w);
    *(ushort4*)(d + i) = o;
  }
}

// ---------------- shared NT-GEMM main loop (m97 structure) ----------------
// A [Arows][768] bf16 row-major, Bw [Nout][768] bf16 row-major (B^T input).
// 128x128 block tile, 4 waves in 2x2, each wave 4x4 of 16x16x32 MFMA, BK=64.
// XOR chunk swizzle (chunk c of row r lives at slot c^(r&7)) applied via the
// *global* address during global_load_lds staging -> conflict-free ds_read_b128.
DEV void gemm_mainloop(const unsigned short* __restrict__ A, int Arows,
                       const unsigned short* __restrict__ Bw,
                       unsigned short* As, unsigned short* Bs,
                       int mbase, int nbase, f32x4 acc[4][4]) {
  const int tid  = threadIdx.x;
  const int lane = tid & 63;
  const int wave = tid >> 6;
  const int wm = wave & 1, wn = wave >> 1;
  const int l16 = lane & 15, quad = lane >> 4;

  for (int k0 = 0; k0 < DIMC; k0 += 64) {
#pragma unroll
    for (int i = 0; i < 4; ++i) {
      int c = i * 256 + tid;          // LDS chunk id 0..1023 (16B chunks)
      int row = c >> 3, cc = c & 7;
      int gc = (cc ^ (row & 7)) * 8;  // swizzled global chunk
      int ar = mbase + row; ar = ar < Arows ? ar : Arows - 1;  // M tail clamp
      async_cp16(A  + (size_t)ar * DIMC + k0 + gc, As + c * 8);
      async_cp16(Bw + (size_t)(nbase + row) * DIMC + k0 + gc, Bs + c * 8);
    }
    __syncthreads();   // compiler drains vmcnt(0) here (covers global_load_lds)
#pragma unroll
    for (int kk = 0; kk < 64; kk += 32) {
      const int cw = (kk >> 3) + quad;
      bf16x8 af[4], bfr[4];
#pragma unroll
      for (int mi = 0; mi < 4; ++mi) {
        int r = wm * 64 + mi * 16 + l16;
        af[mi] = *(const bf16x8*)(As + r * 64 + (cw ^ (r & 7)) * 8);
      }
#pragma unroll
      for (int ni = 0; ni < 4; ++ni) {
        int r = wn * 64 + ni * 16 + l16;
        bfr[ni] = *(const bf16x8*)(Bs + r * 64 + (cw ^ (r & 7)) * 8);
      }
#pragma unroll
      for (int mi = 0; mi < 4; ++mi)
#pragma unroll
        for (int ni = 0; ni < 4; ++ni)
          acc[mi][ni] = mfma16(af[mi], bfr[ni], acc[mi][ni]);
    }
    __syncthreads();
  }
}

// ---------------- QKV GEMM: qkv[t][o] -> bf16 [3][B][H][N][HD] ----------------
__global__ void __launch_bounds__(256) gemm_qkv(const unsigned short* __restrict__ A,
                                                const unsigned short* __restrict__ Bw,
                                                unsigned short* __restrict__ qkv) {
  __shared__ __align__(16) unsigned short As[128 * 64];
  __shared__ __align__(16) unsigned short Bs[128 * 64];
  const int tid = threadIdx.x, lane = tid & 63, wave = tid >> 6;
  const int wm = wave & 1, wn = wave >> 1;
  const int l16 = lane & 15, quad = lane >> 4;
  const int mbase = blockIdx.x * 128, nbase = blockIdx.y * 128;

  f32x4 acc[4][4];
#pragma unroll
  for (int i = 0; i < 4; ++i)
#pragma unroll
    for (int j = 0; j < 4; ++j) acc[i][j] = {0.f, 0.f, 0.f, 0.f};

  gemm_mainloop(A, MTOK, Bw, As, Bs, mbase, nbase, acc);

  // epilogue: scatter C[t][o] as bf16 into [which][b][h][n][hd]
  const int oc64  = nbase + wn * 64;            // 64-aligned -> uniform which/h
  const int which = oc64 / DIMC;
  const int h     = (oc64 % DIMC) / HDIM;
#pragma unroll
  for (int mi = 0; mi < 4; ++mi) {
    int t0 = mbase + wm * 64 + mi * 16 + quad * 4;
#pragma unroll
    for (int r = 0; r < 4; ++r) {
      int t = t0 + r;
      if (t < MTOK) {
        int b = t / NTOK, n = t - b * NTOK;
        size_t base = ((size_t)((which * NB + b) * NH + h) * NTOK + n) * HDIM;
#pragma unroll
        for (int ni = 0; ni < 4; ++ni)
          qkv[base + ni * 16 + l16] = f2bf(acc[mi][ni][r]);
      }
    }
  }
}

// ---------------- Proj GEMM + bias + residual (fp32 out) ----------------
__global__ void __launch_bounds__(256) gemm_proj(const unsigned short* __restrict__ A,
                                                 const unsigned short* __restrict__ Bw,
                                                 const float* __restrict__ bias,
                                                 const float* __restrict__ xres,
                                                 float* __restrict__ out) {
  __shared__ __align__(16) unsigned short As[128 * 64];
  __shared__ __align__(16) unsigned short Bs[128 * 64];
  const int tid = threadIdx.x, lane = tid & 63, wave = tid >> 6;
  const int wm = wave & 1, wn = wave >> 1;
  const int l16 = lane & 15, quad = lane >> 4;
  const int mbase = blockIdx.x * 128, nbase = blockIdx.y * 128;

  f32x4 acc[4][4];
#pragma unroll
  for (int i = 0; i < 4; ++i)
#pragma unroll
    for (int j = 0; j < 4; ++j) acc[i][j] = {0.f, 0.f, 0.f, 0.f};

  gemm_mainloop(A, MTOK, Bw, As, Bs, mbase, nbase, acc);

  const int oc = nbase + wn * 64;
#pragma unroll
  for (int mi = 0; mi < 4; ++mi) {
    int t0 = mbase + wm * 64 + mi * 16 + quad * 4;
#pragma unroll
    for (int r = 0; r < 4; ++r) {
      int t = t0 + r;
      if (t < MTOK) {
        size_t rowb = (size_t)t * DIMC;
#pragma unroll
        for (int ni = 0; ni < 4; ++ni) {
          int o = oc + ni * 16 + l16;
          out[rowb + o] = acc[mi][ni][r] + bias[o] + xres[rowb + o];
        }
      }
    }
  }
}

// ---------------- fused attention, one block per (b,h) ----------------
// Computes S^T = K.Q^T (softmax row = lane&15 -> 2-shfl reductions) and
// O^T = V^T.P^T (V^T A-frags contiguous in LDS). P transposed via per-wave LDS.
__global__ void __launch_bounds__(256) attn_fused(const unsigned short* __restrict__ qkv,
                                                  const float* __restrict__ scale,
                                                  unsigned short* __restrict__ aout) {
  // Ks: [208][64] XOR-chunk-swizzled (26624B). Vt: [64][232] (29696B).
  // Ps: per-wave 16x56-stride P scratch (7168B). Total 63488B < 64KB.
  __shared__ __align__(16) unsigned short Ks[208 * 64];
  __shared__ __align__(16) unsigned short Vt[64 * 232];
  __shared__ __align__(16) unsigned short Ps[4][16 * 56];

  const int bh = blockIdx.x;
  const int b = bh / NH, h = bh - b * NH;
  const int tid = threadIdx.x, lane = tid & 63, wave = tid >> 6;
  const int l16 = lane & 15, quad = lane >> 4;

  const size_t hb = (size_t)bh * (NTOK * HDIM);
  const unsigned short* qg = qkv + hb;
  const unsigned short* kg = qkv + (size_t)(NB * NH) * (NTOK * HDIM) + hb;
  const unsigned short* vg = qkv + (size_t)2 * (NB * NH) * (NTOK * HDIM) + hb;
  const float sc = scale[h];

  // stage K (rows 0..196; rows 197..207 stay garbage -> masked)
  for (int c = tid; c < NTOK * 8; c += 256) {
    int row = c >> 3, cc = c & 7;
    *(float4*)(Ks + row * 64 + ((cc ^ (row & 7)) * 8)) =
        *(const float4*)(kg + (size_t)row * 64 + cc * 8);
  }
  // zero V^T pad cols [197,232) (P there is exactly 0; avoid 0*garbage=NaN)
  for (int i = tid; i < 64 * 35; i += 256) {
    int d = i / 35, jj = i - d * 35;
    Vt[d * 232 + 197 + jj] = 0;
  }
  // stage V transposed
  for (int c = tid; c < NTOK * 8; c += 256) {
    int row = c >> 3, cc = c & 7;
    const unsigned short* src = vg + (size_t)row * 64 + cc * 8;
    ushort4 a0 = *(const ushort4*)(src);
    ushort4 a1 = *(const ushort4*)(src + 4);
    int d0 = cc * 8;
    Vt[(d0 + 0) * 232 + row] = a0.x; Vt[(d0 + 1) * 232 + row] = a0.y;
    Vt[(d0 + 2) * 232 + row] = a0.z; Vt[(d0 + 3) * 232 + row] = a0.w;
    Vt[(d0 + 4) * 232 + row] = a1.x; Vt[(d0 + 5) * 232 + row] = a1.y;
    Vt[(d0 + 6) * 232 + row] = a1.z; Vt[(d0 + 7) * 232 + row] = a1.w;
  }
  __syncthreads();

  for (int mt = wave; mt < 13; mt += 4) {   // Q 16-row tiles, round-robin
    int qr = mt * 16 + l16; if (qr > NTOK - 1) qr = NTOK - 1;   // clamp tail
    bf16x8 qb0 = *(const bf16x8*)(qg + (size_t)qr * 64 + quad * 8);
    bf16x8 qb1 = *(const bf16x8*)(qg + (size_t)qr * 64 + 32 + quad * 8);
    const int mg = mt * 16 + l16;           // global Q row (for diag mask)
    unsigned short* pw = Ps[wave];

    float m_run = -1e30f, l_run = 0.f;
    f32x4 oacc[4];
#pragma unroll
    for (int dt = 0; dt < 4; ++dt) oacc[dt] = {0.f, 0.f, 0.f, 0.f};

    for (int jc = 0; jc < 7; ++jc) {        // 32 K-cols per chunk (224 padded)
      f32x4 s[2];
#pragma unroll
      for (int st = 0; st < 2; ++st) {
        s[st] = {0.f, 0.f, 0.f, 0.f};
        int jrow = (jc * 2 + st) * 16 + l16;       // K row = S^T A-operand row
        const unsigned short* kr = Ks + (size_t)jrow * 64;
        int x0 = (quad ^ (jrow & 7)) * 8;          // un-swizzle chunk (kk=0)
        int x1 = ((4 + quad) ^ (jrow & 7)) * 8;    // kk=32
        bf16x8 ka0 = *(const bf16x8*)(kr + x0);
        bf16x8 ka1 = *(const bf16x8*)(kr + x1);
        s[st] = mfma16(ka0, qb0, s[st]);
        s[st] = mfma16(ka1, qb1, s[st]);
      }
      // scale + diag/pad mask (select: NaN-safe on garbage pad rows)
      float cmax = -1e30f;
#pragma unroll
      for (int st = 0; st < 2; ++st)
#pragma unroll
        for (int r = 0; r < 4; ++r) {
          int jg = jc * 32 + st * 16 + quad * 4 + r;
          float v = s[st][r] * sc;
          v = (jg >= NTOK || jg == mg) ? -1e30f : v;
          s[st][r] = v;
          cmax = fmaxf(cmax, v);
        }
      cmax = fmaxf(cmax, __shfl_xor(cmax, 16));
      cmax = fmaxf(cmax, __shfl_xor(cmax, 32));
      float m_new = fmaxf(m_run, cmax);
      float alpha = __expf(m_run - m_new);
      float psum = 0.f;
#pragma unroll
      for (int st = 0; st < 2; ++st)
#pragma unroll
        for (int r = 0; r < 4; ++r) {
          float e = __expf(s[st][r] - m_new);
          psum += e;
          pw[l16 * 56 + st * 16 + quad * 4 + r] = f2bf(e);  // P^T->P transpose
        }
      psum += __shfl_xor(psum, 16);
      psum += __shfl_xor(psum, 32);
      l_run = l_run * alpha + psum;
      m_run = m_new;
#pragma unroll
      for (int dt = 0; dt < 4; ++dt) {
        oacc[dt][0] *= alpha; oacc[dt][1] *= alpha;
        oacc[dt][2] *= alpha; oacc[dt][3] *= alpha;
      }
      // cross-lane LDS dep within the wave: drain DS queue before readback
      __asm__ __volatile__("s_waitcnt lgkmcnt(0)" ::: "memory");
      bf16x8 pb = *(const bf16x8*)(pw + l16 * 56 + quad * 8);  // P B-frag
#pragma unroll
      for (int dt = 0; dt < 4; ++dt) {
        bf16x8 va = *(const bf16x8*)(Vt + (size_t)(dt * 16 + l16) * 232 +
                                     jc * 32 + quad * 8);      // V^T A-frag
        oacc[dt] = mfma16(va, pb, oacc[dt]);
      }
    }
    // O^T C-layout: lane holds Q-row l16, d = dt*16 + quad*4 + r (consecutive)
    if (mt * 16 + l16 < NTOK) {
      float inv = 1.0f / l_run;
      size_t ob = (size_t)(b * NTOK + mt * 16 + l16) * DIMC + h * HDIM;
#pragma unroll
      for (int dt = 0; dt < 4; ++dt) {
        ushort4 pk;
        pk.x = f2bf(oacc[dt][0] * inv);
        pk.y = f2bf(oacc[dt][1] * inv);
        pk.z = f2bf(oacc[dt][2] * inv);
        pk.w = f2bf(oacc[dt][3] * inv);
        *(ushort4*)(aout + ob + dt * 16 + quad * 4) = pk;
      }
    }
  }
}

// ---------------- launcher ----------------
extern "C" void kernel_launch(void* const* d_in, const int* in_sizes, int n_in,
                              void* d_out, int out_size, void* d_ws, size_t ws_size,
                              hipStream_t stream) {
  const float* x     = (const float*)d_in[0];
  const float* scale = (const float*)d_in[1];
  const float* wqkv  = (const float*)d_in[2];
  const float* wproj = (const float*)d_in[3];
  const float* bproj = (const float*)d_in[4];
  float* out = (float*)d_out;

  // workspace layout (bf16), ~82.2 MB total; attn-out aliases x_bf16 (x_bf16
  // is dead after gemm_qkv; proj residual reads the original fp32 x).
  unsigned short* xb   = (unsigned short*)d_ws;
  unsigned short* wqb  = xb  + (size_t)MTOK * DIMC;   // + 9,682,944
  unsigned short* wpb  = wqb + (size_t)QKVO * DIMC;   // + 1,769,472
  unsigned short* qkvb = wpb + (size_t)DIMC * DIMC;   // +   589,824
  unsigned short* attb = xb;                          // alias

  cvt_bf16<<<(MTOK * DIMC) / 1024, 256, 0, stream>>>(x, xb, MTOK * DIMC);
  cvt_bf16<<<(QKVO * DIMC) / 1024, 256, 0, stream>>>(wqkv, wqb, QKVO * DIMC);
  cvt_bf16<<<(DIMC * DIMC) / 1024, 256, 0, stream>>>(wproj, wpb, DIMC * DIMC);

  gemm_qkv<<<dim3((MTOK + 127) / 128, QKVO / 128), 256, 0, stream>>>(xb, wqb, qkvb);
  attn_fused<<<NB * NH, 256, 0, stream>>>(qkvb, scale, attb);
  gemm_proj<<<dim3((MTOK + 127) / 128, DIMC / 128), 256, 0, stream>>>(attb, wpb, bproj, x, out);
}

// Round 2
// 248.706 us; speedup vs baseline: 1.0367x; 1.0367x over previous
//
#include <hip/hip_runtime.h>
#include <cstdint>
#include <cstddef>

#define DEV static __device__ __forceinline__

typedef __attribute__((ext_vector_type(8))) short bf16x8;   // 8 bf16 (4 VGPRs)
typedef __attribute__((ext_vector_type(4))) float f32x4;

constexpr int NB   = 64;     // batch
constexpr int NTOK = 197;    // tokens
constexpr int DIMC = 768;    // channels
constexpr int NH   = 12;     // heads
constexpr int HDIM = 64;     // head dim
constexpr int MTOK = NB * NTOK;   // 12608 rows
constexpr int QKVO = 3 * DIMC;    // 2304

DEV unsigned short f2bf(float f) {
  union { float f; uint32_t u; } v; v.f = f;
  uint32_t u = v.u;
  return (unsigned short)((u + 0x7FFFu + ((u >> 16) & 1u)) >> 16);  // RNE, finite inputs
}

DEV f32x4 mfma16(bf16x8 a, bf16x8 b, f32x4 c) {
  return __builtin_amdgcn_mfma_f32_16x16x32_bf16(a, b, c, 0, 0, 0);
}

DEV void async_cp16(const unsigned short* g, unsigned short* l) {
  // direct global->LDS DMA, 16B/lane; LDS dest is lane-contiguous (no pad!)
  __builtin_amdgcn_global_load_lds(
      (__attribute__((address_space(1))) void*)g,
      (__attribute__((address_space(3))) void*)l, 16, 0, 0);
}

// supertile swizzle: groups of 8 M-tiles, N-major inside the group, so
// consecutive blocks (round-robin over XCDs) share a 1.5MB A-band + full B.
DEV void swizzle_mn(int lin, int gridM, int gridN, int& mbase, int& nbase) {
  int per = 8 * gridN;
  int sup = lin / per;                 // all leading supertiles are full
  int bm  = sup * 8;
  int Gm  = gridM - bm; if (Gm > 8) Gm = 8;
  int rem = lin - sup * per;
  int n   = rem / Gm;
  int mm  = rem - n * Gm;
  mbase = (bm + mm) * 128;
  nbase = n * 128;
}

// ---------------- f32 -> bf16 convert (memory-bound) ----------------
__global__ void __launch_bounds__(256) cvt_bf16(const float* __restrict__ s,
                                                unsigned short* __restrict__ d, int n) {
  int i = (blockIdx.x * 256 + threadIdx.x) * 4;
  if (i < n) {
    float4 f = *(const float4*)(s + i);
    ushort4 o;
    o.x = f2bf(f.x); o.y = f2bf(f.y); o.z = f2bf(f.z); o.w = f2bf(f.w);
    *(ushort4*)(d + i) = o;
  }
}

// ---------------- shared NT-GEMM main loop (m97 structure) ----------------
// A [Arows][768] bf16 row-major, Bw [Nout][768] bf16 row-major (B^T input).
// 128x128 block tile, 4 waves in 2x2, each wave 4x4 of 16x16x32 MFMA, BK=64.
// XOR chunk swizzle applied via the *global* address during global_load_lds
// staging (LDS fill stays lane-contiguous) -> conflict-free ds_read_b128.
DEV void gemm_mainloop(const unsigned short* __restrict__ A, int Arows,
                       const unsigned short* __restrict__ Bw,
                       unsigned short* As, unsigned short* Bs,
                       int mbase, int nbase, f32x4 acc[4][4]) {
  const int tid  = threadIdx.x;
  const int lane = tid & 63;
  const int wave = tid >> 6;
  const int wm = wave & 1, wn = wave >> 1;
  const int l16 = lane & 15, quad = lane >> 4;

  for (int k0 = 0; k0 < DIMC; k0 += 64) {
#pragma unroll
    for (int i = 0; i < 4; ++i) {
      int c = i * 256 + tid;          // LDS chunk id 0..1023 (16B chunks)
      int row = c >> 3, cc = c & 7;
      int gc = (cc ^ (row & 7)) * 8;  // swizzled global chunk
      int ar = mbase + row; ar = ar < Arows ? ar : Arows - 1;  // M tail clamp
      async_cp16(A  + (size_t)ar * DIMC + k0 + gc, As + c * 8);
      async_cp16(Bw + (size_t)(nbase + row) * DIMC + k0 + gc, Bs + c * 8);
    }
    __syncthreads();   // compiler drains vmcnt(0) here (covers global_load_lds)
#pragma unroll
    for (int kk = 0; kk < 64; kk += 32) {
      const int cw = (kk >> 3) + quad;
      bf16x8 af[4], bfr[4];
#pragma unroll
      for (int mi = 0; mi < 4; ++mi) {
        int r = wm * 64 + mi * 16 + l16;
        af[mi] = *(const bf16x8*)(As + r * 64 + (cw ^ (r & 7)) * 8);
      }
#pragma unroll
      for (int ni = 0; ni < 4; ++ni) {
        int r = wn * 64 + ni * 16 + l16;
        bfr[ni] = *(const bf16x8*)(Bs + r * 64 + (cw ^ (r & 7)) * 8);
      }
#pragma unroll
      for (int mi = 0; mi < 4; ++mi)
#pragma unroll
        for (int ni = 0; ni < 4; ++ni)
          acc[mi][ni] = mfma16(af[mi], bfr[ni], acc[mi][ni]);
    }
    __syncthreads();
  }
}

// ---------------- QKV GEMM: qkv[t][o] -> bf16 [3][B][H][N][HD] ----------------
__global__ void __launch_bounds__(256) gemm_qkv(const unsigned short* __restrict__ A,
                                                const unsigned short* __restrict__ Bw,
                                                unsigned short* __restrict__ qkv,
                                                int gridM, int gridN) {
  __shared__ __align__(16) unsigned short As[128 * 64];
  __shared__ __align__(16) unsigned short Bs[128 * 64];
  const int tid = threadIdx.x, lane = tid & 63, wave = tid >> 6;
  const int wm = wave & 1, wn = wave >> 1;
  const int l16 = lane & 15, quad = lane >> 4;
  int mbase, nbase;
  swizzle_mn(blockIdx.x, gridM, gridN, mbase, nbase);

  f32x4 acc[4][4];
#pragma unroll
  for (int i = 0; i < 4; ++i)
#pragma unroll
    for (int j = 0; j < 4; ++j) acc[i][j] = {0.f, 0.f, 0.f, 0.f};

  gemm_mainloop(A, MTOK, Bw, As, Bs, mbase, nbase, acc);

  // epilogue: scatter C[t][o] as bf16 into [which][b][h][n][hd]
  const int oc64  = nbase + wn * 64;            // 64-aligned -> uniform which/h
  const int which = oc64 / DIMC;
  const int h     = (oc64 % DIMC) / HDIM;
#pragma unroll
  for (int mi = 0; mi < 4; ++mi) {
    int t0 = mbase + wm * 64 + mi * 16 + quad * 4;
#pragma unroll
    for (int r = 0; r < 4; ++r) {
      int t = t0 + r;
      if (t < MTOK) {
        int b = t / NTOK, n = t - b * NTOK;
        size_t base = ((size_t)((which * NB + b) * NH + h) * NTOK + n) * HDIM;
#pragma unroll
        for (int ni = 0; ni < 4; ++ni)
          qkv[base + ni * 16 + l16] = f2bf(acc[mi][ni][r]);
      }
    }
  }
}

// ---------------- Proj GEMM + bias + residual (fp32 out) ----------------
__global__ void __launch_bounds__(256) gemm_proj(const unsigned short* __restrict__ A,
                                                 const unsigned short* __restrict__ Bw,
                                                 const float* __restrict__ bias,
                                                 const float* __restrict__ xres,
                                                 float* __restrict__ out,
                                                 int gridM, int gridN) {
  __shared__ __align__(16) unsigned short As[128 * 64];
  __shared__ __align__(16) unsigned short Bs[128 * 64];
  const int tid = threadIdx.x, lane = tid & 63, wave = tid >> 6;
  const int wm = wave & 1, wn = wave >> 1;
  const int l16 = lane & 15, quad = lane >> 4;
  int mbase, nbase;
  swizzle_mn(blockIdx.x, gridM, gridN, mbase, nbase);

  f32x4 acc[4][4];
#pragma unroll
  for (int i = 0; i < 4; ++i)
#pragma unroll
    for (int j = 0; j < 4; ++j) acc[i][j] = {0.f, 0.f, 0.f, 0.f};

  gemm_mainloop(A, MTOK, Bw, As, Bs, mbase, nbase, acc);

  const int oc = nbase + wn * 64;
#pragma unroll
  for (int mi = 0; mi < 4; ++mi) {
    int t0 = mbase + wm * 64 + mi * 16 + quad * 4;
#pragma unroll
    for (int r = 0; r < 4; ++r) {
      int t = t0 + r;
      if (t < MTOK) {
        size_t rowb = (size_t)t * DIMC;
#pragma unroll
        for (int ni = 0; ni < 4; ++ni) {
          int o = oc + ni * 16 + l16;
          out[rowb + o] = acc[mi][ni][r] + bias[o] + xres[rowb + o];
        }
      }
    }
  }
}

// ---------------- fused attention, one block per (b,h) ----------------
// Non-online softmax: all 224 (padded) scores live in 56 VGPRs per lane.
// S^T = K.Q^T batched (28 MFMAs, K A-frags straight from global/L1), one
// mask/max/exp pass (2 shfls), then O^T = V^T.P^T in two LDS half-passes.
__global__ void __launch_bounds__(256, 3) attn_fused(const unsigned short* __restrict__ qkv,
                                                     const float* __restrict__ scale,
                                                     unsigned short* __restrict__ aout) {
  // Vt: [64][232] V^T (29696B). Ps: per-wave 16x136 P scratch for one
  // 128-key half-pass (17408B). Total 47104B -> 3 blocks/CU.
  __shared__ __align__(16) unsigned short Vt[64 * 232];
  __shared__ __align__(16) unsigned short Ps[4][16 * 136];

  const int bh = blockIdx.x;
  const int b = bh / NH, h = bh - b * NH;
  const int tid = threadIdx.x, lane = tid & 63, wave = tid >> 6;
  const int l16 = lane & 15, quad = lane >> 4;

  const size_t hb = (size_t)bh * (NTOK * HDIM);
  const unsigned short* qg = qkv + hb;
  const unsigned short* kg = qkv + (size_t)(NB * NH) * (NTOK * HDIM) + hb;
  const unsigned short* vg = qkv + (size_t)2 * (NB * NH) * (NTOK * HDIM) + hb;
  const float sc = scale[h];

  // zero V^T pad cols [197,232) (P there is exactly 0; avoid 0*garbage=NaN)
  for (int i = tid; i < 64 * 35; i += 256) {
    int d = i / 35, jj = i - d * 35;
    Vt[d * 232 + 197 + jj] = 0;
  }
  // stage V transposed (one-time; scalar writes, amortized)
  for (int c = tid; c < NTOK * 8; c += 256) {
    int row = c >> 3, cc = c & 7;
    const unsigned short* src = vg + (size_t)row * 64 + cc * 8;
    ushort4 a0 = *(const ushort4*)(src);
    ushort4 a1 = *(const ushort4*)(src + 4);
    int d0 = cc * 8;
    Vt[(d0 + 0) * 232 + row] = a0.x; Vt[(d0 + 1) * 232 + row] = a0.y;
    Vt[(d0 + 2) * 232 + row] = a0.z; Vt[(d0 + 3) * 232 + row] = a0.w;
    Vt[(d0 + 4) * 232 + row] = a1.x; Vt[(d0 + 5) * 232 + row] = a1.y;
    Vt[(d0 + 6) * 232 + row] = a1.z; Vt[(d0 + 7) * 232 + row] = a1.w;
  }
  __syncthreads();

  for (int mt = wave; mt < 13; mt += 4) {   // Q 16-row tiles, round-robin
    int qr = mt * 16 + l16; if (qr > NTOK - 1) qr = NTOK - 1;   // clamp tail
    bf16x8 qb0 = *(const bf16x8*)(qg + (size_t)qr * 64 + quad * 8);
    bf16x8 qb1 = *(const bf16x8*)(qg + (size_t)qr * 64 + 32 + quad * 8);
    const int mg = mt * 16 + l16;           // global Q row (for diag mask)
    unsigned short* pw = Ps[wave];

    // ---- batched S^T: 28 independent MFMAs, K frags from global (L1) ----
    f32x4 s[7][2];
#pragma unroll
    for (int jc = 0; jc < 7; ++jc)
#pragma unroll
      for (int st = 0; st < 2; ++st) {
        int jrow = (jc * 2 + st) * 16 + l16;    // key row (>=197 garbage, masked)
        const unsigned short* kr = kg + (size_t)jrow * 64;
        bf16x8 ka0 = *(const bf16x8*)(kr + quad * 8);
        bf16x8 ka1 = *(const bf16x8*)(kr + 32 + quad * 8);
        f32x4 t = {0.f, 0.f, 0.f, 0.f};
        t = mfma16(ka0, qb0, t);
        t = mfma16(ka1, qb1, t);
        s[jc][st] = t;
      }

    // ---- single softmax pass: scale + mask, max, exp, sum ----
    float cmax = -1e30f;
#pragma unroll
    for (int jc = 0; jc < 7; ++jc)
#pragma unroll
      for (int st = 0; st < 2; ++st)
#pragma unroll
        for (int r = 0; r < 4; ++r) {
          int jg = jc * 32 + st * 16 + quad * 4 + r;
          float v = s[jc][st][r] * sc;
          v = (jg >= NTOK || jg == mg) ? -1e30f : v;   // select: NaN-safe
          s[jc][st][r] = v;
          cmax = fmaxf(cmax, v);
        }
    cmax = fmaxf(cmax, __shfl_xor(cmax, 16));
    cmax = fmaxf(cmax, __shfl_xor(cmax, 32));
    float psum = 0.f;
#pragma unroll
    for (int jc = 0; jc < 7; ++jc)
#pragma unroll
      for (int st = 0; st < 2; ++st)
#pragma unroll
        for (int r = 0; r < 4; ++r) {
          float e = __expf(s[jc][st][r] - cmax);       // masked -> exp -> 0
          psum += e;
          s[jc][st][r] = e;
        }
    psum += __shfl_xor(psum, 16);
    psum += __shfl_xor(psum, 32);
    const float inv = 1.0f / psum;

    // ---- PV: O^T = V^T . P^T, two 128/96-key half-passes through LDS ----
    f32x4 oacc[4];
#pragma unroll
    for (int dt = 0; dt < 4; ++dt) oacc[dt] = {0.f, 0.f, 0.f, 0.f};

    // pass A: keys 0..127 (jc 0..3)
#pragma unroll
    for (int jc = 0; jc < 4; ++jc)
#pragma unroll
      for (int st = 0; st < 2; ++st) {
        ushort4 pk;
        pk.x = f2bf(s[jc][st][0]); pk.y = f2bf(s[jc][st][1]);
        pk.z = f2bf(s[jc][st][2]); pk.w = f2bf(s[jc][st][3]);
        *(ushort4*)(pw + l16 * 136 + jc * 32 + st * 16 + quad * 4) = pk;
      }
    __asm__ __volatile__("s_waitcnt lgkmcnt(0)" ::: "memory");
#pragma unroll
    for (int jc = 0; jc < 4; ++jc) {
      bf16x8 pb = *(const bf16x8*)(pw + l16 * 136 + jc * 32 + quad * 8);
#pragma unroll
      for (int dt = 0; dt < 4; ++dt) {
        bf16x8 va = *(const bf16x8*)(Vt + (size_t)(dt * 16 + l16) * 232 +
                                     jc * 32 + quad * 8);
        oacc[dt] = mfma16(va, pb, oacc[dt]);
      }
    }
    // pass B: keys 128..223 (jc 4..6) — DS ops are in-order per wave, so
    // these writes cannot pass the pass-A reads above.
#pragma unroll
    for (int jc = 4; jc < 7; ++jc)
#pragma unroll
      for (int st = 0; st < 2; ++st) {
        ushort4 pk;
        pk.x = f2bf(s[jc][st][0]); pk.y = f2bf(s[jc][st][1]);
        pk.z = f2bf(s[jc][st][2]); pk.w = f2bf(s[jc][st][3]);
        *(ushort4*)(pw + l16 * 136 + (jc - 4) * 32 + st * 16 + quad * 4) = pk;
      }
    __asm__ __volatile__("s_waitcnt lgkmcnt(0)" ::: "memory");
#pragma unroll
    for (int jc = 4; jc < 7; ++jc) {
      bf16x8 pb = *(const bf16x8*)(pw + l16 * 136 + (jc - 4) * 32 + quad * 8);
#pragma unroll
      for (int dt = 0; dt < 4; ++dt) {
        bf16x8 va = *(const bf16x8*)(Vt + (size_t)(dt * 16 + l16) * 232 +
                                     jc * 32 + quad * 8);
        oacc[dt] = mfma16(va, pb, oacc[dt]);
      }
    }

    // O^T C-layout: lane holds Q-row l16, d = dt*16 + quad*4 + r (consecutive)
    if (mg < NTOK) {
      size_t ob = (size_t)(b * NTOK + mg) * DIMC + h * HDIM;
#pragma unroll
      for (int dt = 0; dt < 4; ++dt) {
        ushort4 pk;
        pk.x = f2bf(oacc[dt][0] * inv);
        pk.y = f2bf(oacc[dt][1] * inv);
        pk.z = f2bf(oacc[dt][2] * inv);
        pk.w = f2bf(oacc[dt][3] * inv);
        *(ushort4*)(aout + ob + dt * 16 + quad * 4) = pk;
      }
    }
  }
}

// ---------------- launcher ----------------
extern "C" void kernel_launch(void* const* d_in, const int* in_sizes, int n_in,
                              void* d_out, int out_size, void* d_ws, size_t ws_size,
                              hipStream_t stream) {
  const float* x     = (const float*)d_in[0];
  const float* scale = (const float*)d_in[1];
  const float* wqkv  = (const float*)d_in[2];
  const float* wproj = (const float*)d_in[3];
  const float* bproj = (const float*)d_in[4];
  float* out = (float*)d_out;

  // workspace layout (bf16); attn-out aliases x_bf16 (dead after gemm_qkv;
  // proj residual reads the original fp32 x).
  unsigned short* xb   = (unsigned short*)d_ws;
  unsigned short* wqb  = xb  + (size_t)MTOK * DIMC;
  unsigned short* wpb  = wqb + (size_t)QKVO * DIMC;
  unsigned short* qkvb = wpb + (size_t)DIMC * DIMC;
  unsigned short* attb = xb;                          // alias

  cvt_bf16<<<(MTOK * DIMC) / 1024, 256, 0, stream>>>(x, xb, MTOK * DIMC);
  cvt_bf16<<<(QKVO * DIMC) / 1024, 256, 0, stream>>>(wqkv, wqb, QKVO * DIMC);
  cvt_bf16<<<(DIMC * DIMC) / 1024, 256, 0, stream>>>(wproj, wpb, DIMC * DIMC);

  const int gmM = (MTOK + 127) / 128;      // 99
  gemm_qkv<<<gmM * (QKVO / 128), 256, 0, stream>>>(xb, wqb, qkvb, gmM, QKVO / 128);
  attn_fused<<<NB * NH, 256, 0, stream>>>(qkvb, scale, attb);
  gemm_proj<<<gmM * (DIMC / 128), 256, 0, stream>>>(attb, wpb, bproj, x, out,
                                                    gmM, DIMC / 128);
}